// Round 1
// baseline (2298.898 us; speedup 1.0000x reference)
//
#include <hip/hip_runtime.h>
#include <math.h>

#define Bq 8
#define Mq 8192
#define Dq 1024
#define Nq 128
#define Fq 4096

// ---------- generic fp32 GEMM: C[Md x Nd] = A[Md x Kd] @ Bw[Kd x Nd] (+bias)(+gelu)
// BM=64 BN=64 BK=16, 256 threads, 4x4 per thread
template<int EPI> // 0 none, 1 bias, 2 bias+gelu(exact)
__global__ __launch_bounds__(256) void gemm_f32(const float* __restrict__ A,
    const float* __restrict__ Bw, const float* __restrict__ bias,
    float* __restrict__ C, int Md, int Nd, int Kd,
    long strideA, long strideB, long strideC)
{
  __shared__ float sA[16][64];
  __shared__ float sB[16][64];
  int b = blockIdx.z;
  const float* Ab = A + (long)b * strideA;
  const float* Bb = Bw + (long)b * strideB;
  float* Cb = C + (long)b * strideC;
  int m0 = blockIdx.x * 64, n0 = blockIdx.y * 64;
  int t = threadIdx.x;
  int tx = t & 15, ty = t >> 4;
  float acc[4][4] = {};
  for (int k0 = 0; k0 < Kd; k0 += 16) {
    {   // A tile 64x16 -> sA[k][m]
      int row = t >> 2;            // e = 4t: row = e/16
      int col = (t & 3) * 4;       // e%16
      float4 v = *(const float4*)(&Ab[(long)(m0 + row) * Kd + k0 + col]);
      sA[col + 0][row] = v.x; sA[col + 1][row] = v.y;
      sA[col + 2][row] = v.z; sA[col + 3][row] = v.w;
    }
    {   // B tile 16x64 -> sB[k][n]
      int row = t >> 4;            // e = 4t: row = e/64
      int col = (t & 15) * 4;
      *(float4*)(&sB[row][col]) = *(const float4*)(&Bb[(long)(k0 + row) * Nd + n0 + col]);
    }
    __syncthreads();
    #pragma unroll
    for (int k = 0; k < 16; ++k) {
      float av[4], bv[4];
      *(float4*)av = *(const float4*)(&sA[k][ty * 4]);
      *(float4*)bv = *(const float4*)(&sB[k][tx * 4]);
      #pragma unroll
      for (int i = 0; i < 4; ++i)
        #pragma unroll
        for (int j = 0; j < 4; ++j)
          acc[i][j] += av[i] * bv[j];
    }
    __syncthreads();
  }
  #pragma unroll
  for (int i = 0; i < 4; ++i) {
    int row = m0 + ty * 4 + i;
    #pragma unroll
    for (int j = 0; j < 4; ++j) {
      int col = n0 + tx * 4 + j;
      float v = acc[i][j];
      if (EPI >= 1) v += bias[col];
      if (EPI == 2) v = 0.5f * v * (1.0f + erff(v * 0.70710678118654752f));
      Cb[(long)row * Nd + col] = v;
    }
  }
}

// ---------- column stats over m for the token-softmax d: per (b,n) max and 1/sum(exp)
__global__ __launch_bounds__(256) void colstats(const float* __restrict__ logits,
    float* __restrict__ cmax, float* __restrict__ cinv)
{
  __shared__ float red[4][64];
  __shared__ float smax[64];
  int b = blockIdx.y;
  int n0 = blockIdx.x * 64;
  int t = threadIdx.x;
  int nf = t & 63, mg = t >> 6;
  const float* Lb = logits + (long)b * Mq * Nq + n0 + nf;
  float mx = -1e30f;
  for (int m = mg; m < Mq; m += 4) mx = fmaxf(mx, Lb[(long)m * Nq]);
  red[mg][nf] = mx;
  __syncthreads();
  if (mg == 0) {
    mx = fmaxf(fmaxf(red[0][nf], red[1][nf]), fmaxf(red[2][nf], red[3][nf]));
    smax[nf] = mx;
  }
  __syncthreads();
  float cm = smax[nf];
  float s = 0.f;
  for (int m = mg; m < Mq; m += 4) s += expf(Lb[(long)m * Nq] - cm);
  red[mg][nf] = s;
  __syncthreads();
  if (mg == 0) {
    s = red[0][nf] + red[1][nf] + red[2][nf] + red[3][nf];
    cmax[b * Nq + n0 + nf] = cm;
    cinv[b * Nq + n0 + nf] = 1.0f / s;
  }
}

// ---------- x_i[b,n,d] = sum_m d[b,m,n] * x[b,m,d], d computed on the fly
// output tile: all 128 n x 64 d per block; BK(m)=32; 256 threads; 8x4 per thread
__global__ __launch_bounds__(256) void xi_gemm(const float* __restrict__ logits,
    const float* __restrict__ x, const float* __restrict__ cmax,
    const float* __restrict__ cinv, float* __restrict__ xi)
{
  __shared__ float sD[32][128];
  __shared__ float sX[32][64];
  __shared__ float sCM[128], sCI[128];
  int b = blockIdx.y;
  int d0 = blockIdx.x * 64;
  int t = threadIdx.x;
  if (t < 128) { sCM[t] = cmax[b * Nq + t]; sCI[t] = cinv[b * Nq + t]; }
  __syncthreads();
  int tx = t & 15, ty = t >> 4;   // cols tx*4 (d), rows ty*8 (n)
  float acc[8][4] = {};
  const float* Lb = logits + (long)b * Mq * Nq;
  const float* Xb = x + (long)b * Mq * Dq;
  for (int m0 = 0; m0 < Mq; m0 += 32) {
    {   // logits 32x128 -> d values
      int row = t >> 3;
      int col = (t & 7) * 16;
      #pragma unroll
      for (int i = 0; i < 16; i += 4) {
        float4 v = *(const float4*)(&Lb[(long)(m0 + row) * Nq + col + i]);
        sD[row][col + i + 0] = expf(v.x - sCM[col + i + 0]) * sCI[col + i + 0];
        sD[row][col + i + 1] = expf(v.y - sCM[col + i + 1]) * sCI[col + i + 1];
        sD[row][col + i + 2] = expf(v.z - sCM[col + i + 2]) * sCI[col + i + 2];
        sD[row][col + i + 3] = expf(v.w - sCM[col + i + 3]) * sCI[col + i + 3];
      }
    }
    {   // x 32x64
      int row = t >> 3;
      int col = (t & 7) * 8;
      const float* src = &Xb[(long)(m0 + row) * Dq + d0 + col];
      *(float4*)(&sX[row][col]) = *(const float4*)(src);
      *(float4*)(&sX[row][col + 4]) = *(const float4*)(src + 4);
    }
    __syncthreads();
    #pragma unroll
    for (int k = 0; k < 32; ++k) {
      float bv[4];
      *(float4*)bv = *(const float4*)(&sX[k][tx * 4]);
      #pragma unroll
      for (int i = 0; i < 8; ++i) {
        float a = sD[k][ty * 8 + i];
        #pragma unroll
        for (int j = 0; j < 4; ++j) acc[i][j] += a * bv[j];
      }
    }
    __syncthreads();
  }
  #pragma unroll
  for (int i = 0; i < 8; ++i) {
    float4 v = { acc[i][0], acc[i][1], acc[i][2], acc[i][3] };
    *(float4*)(&xi[((long)b * Nq + ty * 8 + i) * Dq + d0 + tx * 4]) = v;
  }
}

// ---------- combine: y[b,m,:] = sum_n c[b,m,n] * y_i[b,n,:], c = row-softmax(logits)
// block: 64 m-rows x 128 d-cols; loops n in chunks of 32
__global__ __launch_bounds__(256) void combine(const float* __restrict__ logits,
    const float* __restrict__ yi, float* __restrict__ y)
{
  __shared__ float sL[64][129];
  __shared__ float sY[32][128];
  int b = blockIdx.z;
  int m0 = blockIdx.x * 64;
  int d0 = blockIdx.y * 128;
  int t = threadIdx.x;
  const float* Lb = logits + (long)b * Mq * Nq;
  {   // stage 64x128 logits rows
    int row = t >> 2;
    int col0 = (t & 3) * 32;
    #pragma unroll
    for (int i = 0; i < 32; i += 4) {
      float4 v = *(const float4*)(&Lb[(long)(m0 + row) * Nq + col0 + i]);
      sL[row][col0 + i + 0] = v.x; sL[row][col0 + i + 1] = v.y;
      sL[row][col0 + i + 2] = v.z; sL[row][col0 + i + 3] = v.w;
    }
  }
  __syncthreads();
  {   // in-LDS row softmax (c), 4 threads per row
    int row = t >> 2, sub = t & 3;
    float mx = -1e30f;
    for (int i = sub * 32; i < sub * 32 + 32; ++i) mx = fmaxf(mx, sL[row][i]);
    mx = fmaxf(mx, __shfl_xor(mx, 1));
    mx = fmaxf(mx, __shfl_xor(mx, 2));
    float s = 0.f;
    for (int i = sub * 32; i < sub * 32 + 32; ++i) s += expf(sL[row][i] - mx);
    s += __shfl_xor(s, 1);
    s += __shfl_xor(s, 2);
    float inv = 1.0f / s;
    for (int i = sub * 32; i < sub * 32 + 32; ++i)
      sL[row][i] = expf(sL[row][i] - mx) * inv;
  }
  __syncthreads();
  int tx = t & 31, ty = t >> 5;   // cols tx*4, rows ty*8
  float acc[8][4] = {};
  const float* Yb = yi + (long)b * Nq * Dq;
  for (int nc = 0; nc < Nq; nc += 32) {
    {   // y_i chunk 32 x 128
      int row = t >> 3;
      int col = (t & 7) * 16;
      const float* src = &Yb[(long)(nc + row) * Dq + d0 + col];
      #pragma unroll
      for (int i = 0; i < 16; i += 4)
        *(float4*)(&sY[row][col + i]) = *(const float4*)(src + i);
    }
    __syncthreads();
    #pragma unroll
    for (int k = 0; k < 32; ++k) {
      float bv[4];
      *(float4*)bv = *(const float4*)(&sY[k][tx * 4]);
      #pragma unroll
      for (int i = 0; i < 8; ++i) {
        float a = sL[ty * 8 + i][nc + k];
        #pragma unroll
        for (int j = 0; j < 4; ++j) acc[i][j] += a * bv[j];
      }
    }
    __syncthreads();
  }
  #pragma unroll
  for (int i = 0; i < 8; ++i) {
    float4 v = { acc[i][0], acc[i][1], acc[i][2], acc[i][3] };
    *(float4*)(&y[((long)b * Mq + m0 + ty * 8 + i) * Dq + d0 + tx * 4]) = v;
  }
}

extern "C" void kernel_launch(void* const* d_in, const int* in_sizes, int n_in,
                              void* d_out, int out_size, void* d_ws, size_t ws_size,
                              hipStream_t stream) {
  const float* x   = (const float*)d_in[0];
  const float* phi = (const float*)d_in[1];
  const float* W1  = (const float*)d_in[2];
  const float* b1  = (const float*)d_in[3];
  const float* W2  = (const float*)d_in[4];
  const float* b2  = (const float*)d_in[5];
  float* y = (float*)d_out;

  float* ws     = (float*)d_ws;
  float* logits = ws;                              // B*M*N
  float* cmax   = logits + (size_t)Bq * Mq * Nq;   // B*N
  float* cinv   = cmax + Bq * Nq;                  // B*N
  float* xi     = cinv + Bq * Nq;                  // B*N*D
  float* h      = xi + (size_t)Bq * Nq * Dq;       // B*N*F
  float* yi     = h + (size_t)Bq * Nq * Fq;        // B*N*D

  // 1) logits = X @ phi    (per b: 8192x1024 @ 1024x128)
  gemm_f32<0><<<dim3(Mq / 64, Nq / 64, Bq), 256, 0, stream>>>(
      x, phi, nullptr, logits, Mq, Nq, Dq, (long)Mq * Dq, 0L, (long)Mq * Nq);
  // 2) per-(b,n) column max and 1/sum(exp) over m
  colstats<<<dim3(Nq / 64, Bq), 256, 0, stream>>>(logits, cmax, cinv);
  // 3) x_i = d^T @ X
  xi_gemm<<<dim3(Dq / 64, Bq), 256, 0, stream>>>(logits, x, cmax, cinv, xi);
  // 4) h = gelu(x_i @ W1 + b1)
  gemm_f32<2><<<dim3(Nq / 64, Fq / 64, Bq), 256, 0, stream>>>(
      xi, W1, b1, h, Nq, Fq, Dq, (long)Nq * Dq, 0L, (long)Nq * Fq);
  // 5) y_i = h @ W2 + b2
  gemm_f32<1><<<dim3(Nq / 64, Dq / 64, Bq), 256, 0, stream>>>(
      h, W2, b2, yi, Nq, Dq, Fq, (long)Nq * Fq, 0L, (long)Nq * Dq);
  // 6) y = C @ y_i with in-kernel row softmax for c
  combine<<<dim3(Mq / 64, Dq / 128, Bq), 256, 0, stream>>>(logits, yi, y);
}

// Round 2
// 865.201 us; speedup vs baseline: 2.6571x; 2.6571x over previous
//
#include <hip/hip_runtime.h>
#include <math.h>

#define Bq 8
#define Mq 8192
#define Dq 1024
#define Nq 128
#define Fq 4096

typedef __bf16 bf16x8 __attribute__((ext_vector_type(8)));
typedef float f32x4 __attribute__((ext_vector_type(4)));
union P4 { __bf16 h[4]; unsigned long long u; };

// swizzled LDS offset for [128 rows][64 bf16 cols] tiles: row stride 128 B,
// XOR byte-bits 4-6 with row&7 so ds_read_b128 fragments spread across bank quads
__device__ __forceinline__ int swzoff(int row, int bcol) {
  return row * 128 + (bcol ^ ((row & 7) << 4));
}

// ---------------- logits = X @ phi via bf16 MFMA ----------------
// per block: 128 m x 128 n, K loop over 1024 d in steps of 64
__global__ __launch_bounds__(256) void logits_mfma(
    const float* __restrict__ x, const float* __restrict__ phi,
    float* __restrict__ logits)
{
  __shared__ __align__(16) char sA[16384];  // x tile  [128 m][64 k]
  __shared__ __align__(16) char sP[16384];  // phi^T   [128 n][64 k]
  int mt = blockIdx.x, b = blockIdx.y;
  int m0 = mt * 128;
  int t = threadIdx.x;
  int col = t & 127, half = t >> 7;      // phi staging: n = col
  int arow = t >> 4, ac4 = t & 15;       // x staging
  int w = t >> 6, l = t & 63, la = l & 15, lb = l >> 4;

  f32x4 zero = {0.f, 0.f, 0.f, 0.f};
  f32x4 acc[2][8];
  for (int i = 0; i < 2; ++i) for (int j = 0; j < 8; ++j) acc[i][j] = zero;

  for (int k0 = 0; k0 < Dq; k0 += 64) {
    // stage x rows (m-major, no transpose needed): float4 loads, b64 LDS writes
    #pragma unroll
    for (int i = 0; i < 8; ++i) {
      int row = arow + 16 * i;
      float4 v = *(const float4*)(x + ((long)b * Mq + m0 + row) * Dq + k0 + ac4 * 4);
      P4 p;
      p.h[0] = (__bf16)v.x; p.h[1] = (__bf16)v.y;
      p.h[2] = (__bf16)v.z; p.h[3] = (__bf16)v.w;
      *(unsigned long long*)(sA + swzoff(row, 8 * ac4)) = p.u;
    }
    // stage phi transposed: scalar loads (n in lane order -> coalesced)
    {
      const float* Pp = phi + (long)(k0 + half * 32) * Nq + col;
      #pragma unroll
      for (int i = 0; i < 32; i += 4) {
        float a0 = Pp[(i + 0) * Nq], a1 = Pp[(i + 1) * Nq];
        float a2 = Pp[(i + 2) * Nq], a3 = Pp[(i + 3) * Nq];
        P4 p;
        p.h[0] = (__bf16)a0; p.h[1] = (__bf16)a1;
        p.h[2] = (__bf16)a2; p.h[3] = (__bf16)a3;
        *(unsigned long long*)(sP + swzoff(col, 2 * (half * 32 + i))) = p.u;
      }
    }
    __syncthreads();
    #pragma unroll
    for (int sub = 0; sub < 2; ++sub) {
      int mbyte = sub * 64 + lb * 16;
      bf16x8 af0 = *(const bf16x8*)(sA + swzoff(w * 32 + la, mbyte));
      bf16x8 af1 = *(const bf16x8*)(sA + swzoff(w * 32 + 16 + la, mbyte));
      bf16x8 bv[8];
      #pragma unroll
      for (int j = 0; j < 8; ++j)
        bv[j] = *(const bf16x8*)(sP + swzoff(j * 16 + la, mbyte));
      #pragma unroll
      for (int j = 0; j < 8; ++j) {
        acc[0][j] = __builtin_amdgcn_mfma_f32_16x16x32_bf16(af0, bv[j], acc[0][j], 0, 0, 0);
        acc[1][j] = __builtin_amdgcn_mfma_f32_16x16x32_bf16(af1, bv[j], acc[1][j], 0, 0, 0);
      }
    }
    __syncthreads();
  }
  float* O = logits + ((long)b * Mq + m0) * Nq;
  #pragma unroll
  for (int i = 0; i < 2; ++i)
    #pragma unroll
    for (int j = 0; j < 8; ++j)
      #pragma unroll
      for (int r = 0; r < 4; ++r)
        O[(long)(w * 32 + i * 16 + lb * 4 + r) * Nq + j * 16 + la] = acc[i][j][r];
}

// ---------------- column softmax denominator (max-free: |logits| <~ 6) ----------------
__global__ __launch_bounds__(256) void colsum_part(const float* __restrict__ logits,
                                                   float* __restrict__ psum)
{
  __shared__ float red[256];
  int chunk = blockIdx.x, b = blockIdx.y;
  int t = threadIdx.x, n = t & 127, half = t >> 7;
  const float* Lp = logits + ((long)b * Mq + chunk * 512 + half * 256) * Nq + n;
  float s = 0.f;
  for (int i = 0; i < 256; ++i) s += __expf(Lp[(long)i * Nq]);
  red[t] = s;
  __syncthreads();
  if (t < 128) psum[((long)chunk * Bq + b) * Nq + n] = red[t] + red[t + 128];
}

__global__ void colsum_fin(const float* __restrict__ psum, float* __restrict__ cinv)
{
  int b = blockIdx.x, n = threadIdx.x;
  float s = 0.f;
  for (int k = 0; k < 16; ++k) s += psum[((long)k * Bq + b) * Nq + n];
  cinv[b * Nq + n] = 1.0f / s;
}

// ---------------- x_i = d^T @ X via bf16 MFMA, split-K over m ----------------
// block: 128 n x 128 d, m-chunk of 1024; writes fp32 partial to part[kc][b][n][d]
__global__ __launch_bounds__(256) void xi_mfma(
    const float* __restrict__ logits, const float* __restrict__ x,
    const float* __restrict__ cinv, float* __restrict__ part)
{
  __shared__ __align__(16) char sD[16384];  // d weights^T [128 n][64 m]
  __shared__ __align__(16) char sX[16384];  // x^T        [128 d][64 m]
  int dt = blockIdx.x, kc = blockIdx.y, b = blockIdx.z;
  int d0 = dt * 128;
  int t = threadIdx.x;
  int col = t & 127, half = t >> 7;
  float civ = cinv[b * Nq + col];
  const float* Lp0 = logits + ((long)b * Mq + (long)kc * 1024 + half * 32) * Nq + col;
  const float* Xp0 = x + ((long)b * Mq + (long)kc * 1024 + half * 32) * Dq + d0 + col;
  int w = t >> 6, l = t & 63, la = l & 15, lb = l >> 4;

  f32x4 zero = {0.f, 0.f, 0.f, 0.f};
  f32x4 acc[2][8];
  for (int i = 0; i < 2; ++i) for (int j = 0; j < 8; ++j) acc[i][j] = zero;

  for (int it = 0; it < 16; ++it) {
    const float* Lp = Lp0 + (long)it * 64 * Nq;
    const float* Xp = Xp0 + (long)it * 64 * Dq;
    #pragma unroll
    for (int i = 0; i < 32; i += 4) {
      float a0 = Lp[(i + 0) * Nq], a1 = Lp[(i + 1) * Nq];
      float a2 = Lp[(i + 2) * Nq], a3 = Lp[(i + 3) * Nq];
      P4 p;
      p.h[0] = (__bf16)(__expf(a0) * civ);
      p.h[1] = (__bf16)(__expf(a1) * civ);
      p.h[2] = (__bf16)(__expf(a2) * civ);
      p.h[3] = (__bf16)(__expf(a3) * civ);
      *(unsigned long long*)(sD + swzoff(col, 2 * (half * 32 + i))) = p.u;
      float b0 = Xp[(i + 0) * Dq], b1 = Xp[(i + 1) * Dq];
      float b2 = Xp[(i + 2) * Dq], b3 = Xp[(i + 3) * Dq];
      P4 q;
      q.h[0] = (__bf16)b0; q.h[1] = (__bf16)b1;
      q.h[2] = (__bf16)b2; q.h[3] = (__bf16)b3;
      *(unsigned long long*)(sX + swzoff(col, 2 * (half * 32 + i))) = q.u;
    }
    __syncthreads();
    #pragma unroll
    for (int sub = 0; sub < 2; ++sub) {
      int mbyte = sub * 64 + lb * 16;
      bf16x8 af0 = *(const bf16x8*)(sD + swzoff(w * 32 + la, mbyte));
      bf16x8 af1 = *(const bf16x8*)(sD + swzoff(w * 32 + 16 + la, mbyte));
      bf16x8 bv[8];
      #pragma unroll
      for (int j = 0; j < 8; ++j)
        bv[j] = *(const bf16x8*)(sX + swzoff(j * 16 + la, mbyte));
      #pragma unroll
      for (int j = 0; j < 8; ++j) {
        acc[0][j] = __builtin_amdgcn_mfma_f32_16x16x32_bf16(af0, bv[j], acc[0][j], 0, 0, 0);
        acc[1][j] = __builtin_amdgcn_mfma_f32_16x16x32_bf16(af1, bv[j], acc[1][j], 0, 0, 0);
      }
    }
    __syncthreads();
  }
  float* P = part + (((long)kc * Bq + b) * Nq) * (long)Dq + d0;
  #pragma unroll
  for (int i = 0; i < 2; ++i)
    #pragma unroll
    for (int j = 0; j < 8; ++j)
      #pragma unroll
      for (int r = 0; r < 4; ++r)
        P[(long)(w * 32 + i * 16 + lb * 4 + r) * Dq + j * 16 + la] = acc[i][j][r];
}

__global__ __launch_bounds__(256) void xi_reduce(const float* __restrict__ part,
                                                 float* __restrict__ xi)
{
  long idx = (long)blockIdx.x * 256 + threadIdx.x;  // over B*N*D/4 float4s
  const float4* p = (const float4*)part;
  float4 s = p[idx];
  #pragma unroll
  for (int k = 1; k < 8; ++k) {
    float4 v = p[(long)k * 262144 + idx];
    s.x += v.x; s.y += v.y; s.z += v.z; s.w += v.w;
  }
  ((float4*)xi)[idx] = s;
}

// ---------- generic fp32 GEMM (kept for the small MLP matmuls) ----------
template<int EPI> // 0 none, 1 bias, 2 bias+gelu(exact)
__global__ __launch_bounds__(256) void gemm_f32(const float* __restrict__ A,
    const float* __restrict__ Bw, const float* __restrict__ bias,
    float* __restrict__ C, int Md, int Nd, int Kd,
    long strideA, long strideB, long strideC)
{
  __shared__ float sA[16][64];
  __shared__ float sB[16][64];
  int b = blockIdx.z;
  const float* Ab = A + (long)b * strideA;
  const float* Bb = Bw + (long)b * strideB;
  float* Cb = C + (long)b * strideC;
  int m0 = blockIdx.x * 64, n0 = blockIdx.y * 64;
  int t = threadIdx.x;
  int tx = t & 15, ty = t >> 4;
  float acc[4][4] = {};
  for (int k0 = 0; k0 < Kd; k0 += 16) {
    {
      int row = t >> 2;
      int colq = (t & 3) * 4;
      float4 v = *(const float4*)(&Ab[(long)(m0 + row) * Kd + k0 + colq]);
      sA[colq + 0][row] = v.x; sA[colq + 1][row] = v.y;
      sA[colq + 2][row] = v.z; sA[colq + 3][row] = v.w;
    }
    {
      int row = t >> 4;
      int colq = (t & 15) * 4;
      *(float4*)(&sB[row][colq]) = *(const float4*)(&Bb[(long)(k0 + row) * Nd + n0 + colq]);
    }
    __syncthreads();
    #pragma unroll
    for (int k = 0; k < 16; ++k) {
      float av[4], bv[4];
      *(float4*)av = *(const float4*)(&sA[k][ty * 4]);
      *(float4*)bv = *(const float4*)(&sB[k][tx * 4]);
      #pragma unroll
      for (int i = 0; i < 4; ++i)
        #pragma unroll
        for (int j = 0; j < 4; ++j)
          acc[i][j] += av[i] * bv[j];
    }
    __syncthreads();
  }
  #pragma unroll
  for (int i = 0; i < 4; ++i) {
    int row = m0 + ty * 4 + i;
    #pragma unroll
    for (int j = 0; j < 4; ++j) {
      int colq = n0 + tx * 4 + j;
      float v = acc[i][j];
      if (EPI >= 1) v += bias[colq];
      if (EPI == 2) v = 0.5f * v * (1.0f + erff(v * 0.70710678118654752f));
      Cb[(long)row * Nd + colq] = v;
    }
  }
}

// ---------- combine: y = C @ y_i with in-LDS row softmax for c ----------
__global__ __launch_bounds__(256) void combine(const float* __restrict__ logits,
    const float* __restrict__ yi, float* __restrict__ y)
{
  __shared__ float sL[64][129];
  __shared__ float sY[32][128];
  int b = blockIdx.z;
  int m0 = blockIdx.x * 64;
  int d0 = blockIdx.y * 128;
  int t = threadIdx.x;
  const float* Lb = logits + (long)b * Mq * Nq;
  {
    int row = t >> 2;
    int col0 = (t & 3) * 32;
    #pragma unroll
    for (int i = 0; i < 32; i += 4) {
      float4 v = *(const float4*)(&Lb[(long)(m0 + row) * Nq + col0 + i]);
      sL[row][col0 + i + 0] = v.x; sL[row][col0 + i + 1] = v.y;
      sL[row][col0 + i + 2] = v.z; sL[row][col0 + i + 3] = v.w;
    }
  }
  __syncthreads();
  {
    int row = t >> 2, sub = t & 3;
    float mx = -1e30f;
    for (int i = sub * 32; i < sub * 32 + 32; ++i) mx = fmaxf(mx, sL[row][i]);
    mx = fmaxf(mx, __shfl_xor(mx, 1));
    mx = fmaxf(mx, __shfl_xor(mx, 2));
    float s = 0.f;
    for (int i = sub * 32; i < sub * 32 + 32; ++i) s += __expf(sL[row][i] - mx);
    s += __shfl_xor(s, 1);
    s += __shfl_xor(s, 2);
    float inv = 1.0f / s;
    for (int i = sub * 32; i < sub * 32 + 32; ++i)
      sL[row][i] = __expf(sL[row][i] - mx) * inv;
  }
  __syncthreads();
  int tx = t & 31, ty = t >> 5;
  float acc[8][4] = {};
  const float* Yb = yi + (long)b * Nq * Dq;
  for (int nc = 0; nc < Nq; nc += 32) {
    {
      int row = t >> 3;
      int col = (t & 7) * 16;
      const float* src = &Yb[(long)(nc + row) * Dq + d0 + col];
      #pragma unroll
      for (int i = 0; i < 16; i += 4)
        *(float4*)(&sY[row][col + i]) = *(const float4*)(src + i);
    }
    __syncthreads();
    #pragma unroll
    for (int k = 0; k < 32; ++k) {
      float bv[4];
      *(float4*)bv = *(const float4*)(&sY[k][tx * 4]);
      #pragma unroll
      for (int i = 0; i < 8; ++i) {
        float a = sL[ty * 8 + i][nc + k];
        #pragma unroll
        for (int j = 0; j < 4; ++j) acc[i][j] += a * bv[j];
      }
    }
    __syncthreads();
  }
  #pragma unroll
  for (int i = 0; i < 8; ++i) {
    float4 v = { acc[i][0], acc[i][1], acc[i][2], acc[i][3] };
    *(float4*)(&y[((long)b * Mq + m0 + ty * 8 + i) * Dq + d0 + tx * 4]) = v;
  }
}

extern "C" void kernel_launch(void* const* d_in, const int* in_sizes, int n_in,
                              void* d_out, int out_size, void* d_ws, size_t ws_size,
                              hipStream_t stream) {
  const float* x   = (const float*)d_in[0];
  const float* phi = (const float*)d_in[1];
  const float* W1  = (const float*)d_in[2];
  const float* b1  = (const float*)d_in[3];
  const float* W2  = (const float*)d_in[4];
  const float* b2  = (const float*)d_in[5];
  float* y = (float*)d_out;

  float* ws     = (float*)d_ws;
  float* logits = ws;                       // 8,388,608
  float* cinv   = logits + 8388608;         // 1,024
  float* psum   = cinv + 1024;              // 16,384
  float* xi     = psum + 16384;             // 1,048,576
  float* part   = xi + 1048576;             // 8,388,608
  float* h      = part;                     // aliases part (part dead after xi_reduce)
  float* yi     = h + 4194304;              // 1,048,576 (inside part region)

  // 1) logits = X @ phi  (bf16 MFMA)
  logits_mfma<<<dim3(Mq / 128, Bq), 256, 0, stream>>>(x, phi, logits);
  // 2) column softmax denominators (max-free)
  colsum_part<<<dim3(16, Bq), 256, 0, stream>>>(logits, psum);
  colsum_fin<<<Bq, 128, 0, stream>>>(psum, cinv);
  // 3) x_i = d^T @ X  (bf16 MFMA, split-K) + reduce
  xi_mfma<<<dim3(Dq / 128, 8, Bq), 256, 0, stream>>>(logits, x, cinv, part);
  xi_reduce<<<1024, 256, 0, stream>>>(part, xi);
  // 4) h = gelu(x_i @ W1 + b1)
  gemm_f32<2><<<dim3(2, Fq / 64, Bq), 256, 0, stream>>>(
      xi, W1, b1, h, Nq, Fq, Dq, (long)Nq * Dq, 0L, (long)Nq * Fq);
  // 5) y_i = h @ W2 + b2
  gemm_f32<1><<<dim3(2, Dq / 64, Bq), 256, 0, stream>>>(
      h, W2, b2, yi, Nq, Dq, Fq, (long)Nq * Fq, 0L, (long)Nq * Dq);
  // 6) y = C @ y_i with in-kernel row softmax for c
  combine<<<dim3(Mq / 64, Dq / 128, Bq), 256, 0, stream>>>(logits, yi, y);
}

// Round 3
// 442.380 us; speedup vs baseline: 5.1967x; 1.9558x over previous
//
#include <hip/hip_runtime.h>
#include <math.h>

#define Bq 8
#define Mq 8192
#define Dq 1024
#define Nq 128
#define Fq 4096

typedef __bf16 bf16x8 __attribute__((ext_vector_type(8)));
typedef float f32x4 __attribute__((ext_vector_type(4)));
union P4 { __bf16 h[4]; unsigned long long u; };

// swizzled LDS offsets: XOR byte-bits 4-6 with row&7 (bank spread for ds_read_b128)
__device__ __forceinline__ int swz128(int row, int bcol) {  // rows of 64 bf16 (128 B)
  return row * 128 + (bcol ^ ((row & 7) << 4));
}
__device__ __forceinline__ int swz256(int row, int bcol) {  // rows of 128 bf16 (256 B)
  return row * 256 + (bcol ^ ((row & 7) << 4));
}

// ---------------- weight fp32 -> bf16 ----------------
__global__ __launch_bounds__(256) void wconv(const float* __restrict__ src,
                                             unsigned long long* __restrict__ dst, long n4)
{
  long i = (long)blockIdx.x * 256 + threadIdx.x;
  if (i >= n4) return;
  float4 v = ((const float4*)src)[i];
  P4 p; p.h[0] = (__bf16)v.x; p.h[1] = (__bf16)v.y; p.h[2] = (__bf16)v.z; p.h[3] = (__bf16)v.w;
  dst[i] = p.u;
}

// ---------------- logits = X @ phi via bf16 MFMA; epilogue: ebuf=exp(l), cbuf=row-softmax ----------------
__global__ __launch_bounds__(256) void logits_mfma(
    const float* __restrict__ x, const float* __restrict__ phi,
    __bf16* __restrict__ ebuf, __bf16* __restrict__ cbuf)
{
  __shared__ __align__(16) char sA[16384];  // x tile  [128 m][64 k]
  __shared__ __align__(16) char sP[16384];  // phi^T   [128 n][64 k]
  int mt = blockIdx.x, b = blockIdx.y;
  int m0 = mt * 128;
  int t = threadIdx.x;
  int col = t & 127, half = t >> 7;
  int arow = t >> 4, ac4 = t & 15;
  int w = t >> 6, l = t & 63, la = l & 15, lb = l >> 4;

  f32x4 zero = {0.f, 0.f, 0.f, 0.f};
  f32x4 acc[2][8];
  for (int i = 0; i < 2; ++i) for (int j = 0; j < 8; ++j) acc[i][j] = zero;

  for (int k0 = 0; k0 < Dq; k0 += 64) {
    #pragma unroll
    for (int i = 0; i < 8; ++i) {
      int row = arow + 16 * i;
      float4 v = *(const float4*)(x + ((long)b * Mq + m0 + row) * Dq + k0 + ac4 * 4);
      P4 p;
      p.h[0] = (__bf16)v.x; p.h[1] = (__bf16)v.y;
      p.h[2] = (__bf16)v.z; p.h[3] = (__bf16)v.w;
      *(unsigned long long*)(sA + swz128(row, 8 * ac4)) = p.u;
    }
    {
      const float* Pp = phi + (long)(k0 + half * 32) * Nq + col;
      #pragma unroll
      for (int i = 0; i < 32; i += 4) {
        float a0 = Pp[(i + 0) * Nq], a1 = Pp[(i + 1) * Nq];
        float a2 = Pp[(i + 2) * Nq], a3 = Pp[(i + 3) * Nq];
        P4 p;
        p.h[0] = (__bf16)a0; p.h[1] = (__bf16)a1;
        p.h[2] = (__bf16)a2; p.h[3] = (__bf16)a3;
        *(unsigned long long*)(sP + swz128(col, 2 * (half * 32 + i))) = p.u;
      }
    }
    __syncthreads();
    #pragma unroll
    for (int sub = 0; sub < 2; ++sub) {
      int mbyte = sub * 64 + lb * 16;
      bf16x8 af0 = *(const bf16x8*)(sA + swz128(w * 32 + la, mbyte));
      bf16x8 af1 = *(const bf16x8*)(sA + swz128(w * 32 + 16 + la, mbyte));
      bf16x8 bv[8];
      #pragma unroll
      for (int j = 0; j < 8; ++j)
        bv[j] = *(const bf16x8*)(sP + swz128(j * 16 + la, mbyte));
      #pragma unroll
      for (int j = 0; j < 8; ++j) {
        acc[0][j] = __builtin_amdgcn_mfma_f32_16x16x32_bf16(af0, bv[j], acc[0][j], 0, 0, 0);
        acc[1][j] = __builtin_amdgcn_mfma_f32_16x16x32_bf16(af1, bv[j], acc[1][j], 0, 0, 0);
      }
    }
    __syncthreads();
  }
  // epilogue: per-row (m) softmax over all 128 n (max-free, |l| <~ 6)
  float inv[2][4];
  #pragma unroll
  for (int i = 0; i < 2; ++i)
    #pragma unroll
    for (int r = 0; r < 4; ++r) {
      float s = 0.f;
      #pragma unroll
      for (int j = 0; j < 8; ++j) s += __expf(acc[i][j][r]);
      s += __shfl_xor(s, 1); s += __shfl_xor(s, 2);
      s += __shfl_xor(s, 4); s += __shfl_xor(s, 8);
      inv[i][r] = 1.0f / s;
    }
  __bf16* Eb = ebuf + ((long)b * Mq + m0) * Nq;
  __bf16* Cb = cbuf + ((long)b * Mq + m0) * Nq;
  #pragma unroll
  for (int i = 0; i < 2; ++i)
    #pragma unroll
    for (int j = 0; j < 8; ++j)
      #pragma unroll
      for (int r = 0; r < 4; ++r) {
        int row = w * 32 + i * 16 + lb * 4 + r;
        int colg = j * 16 + la;
        float e = __expf(acc[i][j][r]);
        Eb[(long)row * Nq + colg] = (__bf16)e;
        Cb[(long)row * Nq + colg] = (__bf16)(e * inv[i][r]);
      }
}

// ---------------- column sums of ebuf over m -> cinv ----------------
__global__ __launch_bounds__(256) void colsum_part(const __bf16* __restrict__ ebuf,
                                                   float* __restrict__ psum)
{
  __shared__ float red[256];
  int chunk = blockIdx.x, b = blockIdx.y;
  int t = threadIdx.x, n = t & 127, half = t >> 7;
  const __bf16* Ep = ebuf + ((long)b * Mq + chunk * 256 + half * 128) * Nq + n;
  float s = 0.f;
  for (int i = 0; i < 128; ++i) s += (float)Ep[(long)i * Nq];
  red[t] = s;
  __syncthreads();
  if (t < 128) psum[((long)chunk * Bq + b) * Nq + n] = red[t] + red[t + 128];
}

__global__ void colsum_fin(const float* __restrict__ psum, float* __restrict__ cinv)
{
  int b = blockIdx.x, n = threadIdx.x;
  float s = 0.f;
  for (int k = 0; k < 32; ++k) s += psum[((long)k * Bq + b) * Nq + n];
  cinv[b * Nq + n] = 1.0f / s;
}

// ---------------- raw xi partials: part[kc][b][n][d] = sum_m ebuf[m,n]*x[m,d] ----------------
// block: 128 n x 64 d, m-chunk 2048 (kc of 4)
__global__ __launch_bounds__(256) void xi_mfma(
    const __bf16* __restrict__ ebuf, const float* __restrict__ x,
    float* __restrict__ part)
{
  __shared__ __align__(16) char sD[16384];  // e^T [128 n][64 m]
  __shared__ __align__(16) char sX[8192];   // x^T [64 d][64 m]
  int dt = blockIdx.x, kc = blockIdx.y, b = blockIdx.z;
  int d0 = dt * 64;
  int t = threadIdx.x;
  int col = t & 127, half = t >> 7;       // A staging (n)
  int cd = t & 63, grp = t >> 6;          // B staging (d, m-group)
  const __bf16* Ep0 = ebuf + ((long)b * Mq + (long)kc * 2048 + half * 32) * Nq + col;
  const float* Xp0 = x + ((long)b * Mq + (long)kc * 2048 + grp * 16) * Dq + d0 + cd;
  int w = t >> 6, l = t & 63, la = l & 15, lb = l >> 4;

  f32x4 zero = {0.f, 0.f, 0.f, 0.f};
  f32x4 acc[2][4];
  for (int i = 0; i < 2; ++i) for (int j = 0; j < 4; ++j) acc[i][j] = zero;

  for (int it = 0; it < 32; ++it) {
    const __bf16* Ep = Ep0 + (long)it * 64 * Nq;
    const float* Xp = Xp0 + (long)it * 64 * Dq;
    #pragma unroll
    for (int i = 0; i < 32; i += 4) {
      P4 p;
      p.h[0] = Ep[(long)(i + 0) * Nq]; p.h[1] = Ep[(long)(i + 1) * Nq];
      p.h[2] = Ep[(long)(i + 2) * Nq]; p.h[3] = Ep[(long)(i + 3) * Nq];
      *(unsigned long long*)(sD + swz128(col, 2 * (half * 32 + i))) = p.u;
    }
    #pragma unroll
    for (int i = 0; i < 16; i += 4) {
      float b0 = Xp[(long)(i + 0) * Dq], b1 = Xp[(long)(i + 1) * Dq];
      float b2 = Xp[(long)(i + 2) * Dq], b3 = Xp[(long)(i + 3) * Dq];
      P4 q;
      q.h[0] = (__bf16)b0; q.h[1] = (__bf16)b1;
      q.h[2] = (__bf16)b2; q.h[3] = (__bf16)b3;
      *(unsigned long long*)(sX + swz128(cd, 2 * (grp * 16 + i))) = q.u;
    }
    __syncthreads();
    #pragma unroll
    for (int sub = 0; sub < 2; ++sub) {
      int mbyte = sub * 64 + lb * 16;
      bf16x8 af0 = *(const bf16x8*)(sD + swz128(w * 32 + la, mbyte));
      bf16x8 af1 = *(const bf16x8*)(sD + swz128(w * 32 + 16 + la, mbyte));
      bf16x8 bv[4];
      #pragma unroll
      for (int j = 0; j < 4; ++j)
        bv[j] = *(const bf16x8*)(sX + swz128(j * 16 + la, mbyte));
      #pragma unroll
      for (int j = 0; j < 4; ++j) {
        acc[0][j] = __builtin_amdgcn_mfma_f32_16x16x32_bf16(af0, bv[j], acc[0][j], 0, 0, 0);
        acc[1][j] = __builtin_amdgcn_mfma_f32_16x16x32_bf16(af1, bv[j], acc[1][j], 0, 0, 0);
      }
    }
    __syncthreads();
  }
  float* P = part + ((long)kc * Bq + b) * Nq * (long)Dq + d0;
  #pragma unroll
  for (int i = 0; i < 2; ++i)
    #pragma unroll
    for (int j = 0; j < 4; ++j)
      #pragma unroll
      for (int r = 0; r < 4; ++r)
        P[(long)(w * 32 + i * 16 + lb * 4 + r) * Dq + j * 16 + la] = acc[i][j][r];
}

// ---------------- xi reduce: xib = bf16(cinv[row] * sum_kc part) ----------------
__global__ __launch_bounds__(256) void xi_reduce(const float* __restrict__ part,
    const float* __restrict__ cinv, __bf16* __restrict__ xib)
{
  long idx = (long)blockIdx.x * 256 + threadIdx.x;   // 1,048,576 elements
  int row = (int)(idx >> 10);
  float civ = cinv[row];
  float s = part[idx] + part[idx + 1048576] + part[idx + 2097152] + part[idx + 3145728];
  xib[idx] = (__bf16)(s * civ);
}

// ---------------- generic bf16 MFMA GEMM 128x128 tile ----------------
// A [.][lda] bf16 row-major, B [.][ldb] bf16 row-major (transpose-staged)
// EPI: 0 = raw fp32 store, 2 = +bias, exact gelu, bf16 store
template<int EPI, typename OT>
__global__ __launch_bounds__(256) void gemm_bf16(const __bf16* __restrict__ A,
    const __bf16* __restrict__ Bw, const float* __restrict__ bias,
    OT* __restrict__ C, int lda, int ldb, int ldc, int kLen, long strideCz)
{
  __shared__ __align__(16) char sA[16384];
  __shared__ __align__(16) char sB[16384];
  int m0 = blockIdx.x * 128, n0 = blockIdx.y * 128;
  int kbase = blockIdx.z * kLen;
  C += (long)blockIdx.z * strideCz;
  int t = threadIdx.x;
  int col = t & 127, half = t >> 7;
  int w = t >> 6, l = t & 63, la = l & 15, lb = l >> 4;

  f32x4 zero = {0.f, 0.f, 0.f, 0.f};
  f32x4 acc[2][8];
  for (int i = 0; i < 2; ++i) for (int j = 0; j < 8; ++j) acc[i][j] = zero;

  for (int kt = 0; kt < kLen; kt += 64) {
    int kp = kbase + kt;
    #pragma unroll
    for (int s = 0; s < 4; ++s) {
      int idx = t + 256 * s;
      int row = idx >> 3, c8 = idx & 7;
      *(int4*)(sA + swz128(row, c8 * 16)) =
          *(const int4*)(A + (long)(m0 + row) * lda + kp + c8 * 8);
    }
    {
      const __bf16* Bp = Bw + (long)(kp + half * 32) * ldb + n0 + col;
      #pragma unroll
      for (int i = 0; i < 32; i += 4) {
        P4 p;
        p.h[0] = Bp[(long)(i + 0) * ldb]; p.h[1] = Bp[(long)(i + 1) * ldb];
        p.h[2] = Bp[(long)(i + 2) * ldb]; p.h[3] = Bp[(long)(i + 3) * ldb];
        *(unsigned long long*)(sB + swz128(col, 2 * (half * 32 + i))) = p.u;
      }
    }
    __syncthreads();
    #pragma unroll
    for (int sub = 0; sub < 2; ++sub) {
      int mbyte = sub * 64 + lb * 16;
      bf16x8 af0 = *(const bf16x8*)(sA + swz128(w * 32 + la, mbyte));
      bf16x8 af1 = *(const bf16x8*)(sA + swz128(w * 32 + 16 + la, mbyte));
      bf16x8 bv[8];
      #pragma unroll
      for (int j = 0; j < 8; ++j)
        bv[j] = *(const bf16x8*)(sB + swz128(j * 16 + la, mbyte));
      #pragma unroll
      for (int j = 0; j < 8; ++j) {
        acc[0][j] = __builtin_amdgcn_mfma_f32_16x16x32_bf16(af0, bv[j], acc[0][j], 0, 0, 0);
        acc[1][j] = __builtin_amdgcn_mfma_f32_16x16x32_bf16(af1, bv[j], acc[1][j], 0, 0, 0);
      }
    }
    __syncthreads();
  }
  #pragma unroll
  for (int i = 0; i < 2; ++i)
    #pragma unroll
    for (int j = 0; j < 8; ++j)
      #pragma unroll
      for (int r = 0; r < 4; ++r) {
        int row = m0 + w * 32 + i * 16 + lb * 4 + r;
        int colg = n0 + j * 16 + la;
        float v = acc[i][j][r];
        if (EPI == 2) {
          v += bias[colg];
          v = 0.5f * v * (1.0f + erff(v * 0.70710678118654752f));
        }
        C[(long)row * ldc + colg] = (OT)v;
      }
}

// ---------------- G2 reduce: yiT[b][d][n] = bf16(sum_kc part + b2[d]) ----------------
__global__ __launch_bounds__(256) void g2_reduce(const float* __restrict__ part,
    const float* __restrict__ b2, __bf16* __restrict__ yiT)
{
  long idx = (long)blockIdx.x * 256 + threadIdx.x;   // 1,048,576
  int row = (int)(idx >> 10);       // b*128+n
  int d = (int)(idx & 1023);
  float s = part[idx] + part[idx + 1048576] + part[idx + 2097152] + part[idx + 3145728] + b2[d];
  int b = row >> 7, n = row & 127;
  yiT[((long)b * Dq + d) * Nq + n] = (__bf16)s;
}

// ---------------- combine: y[b,m,d] = sum_n cbuf[m,n] * yiT[d,n] (bf16 MFMA, K=128) ----------------
__global__ __launch_bounds__(256) void combine_mfma(const __bf16* __restrict__ cbuf,
    const __bf16* __restrict__ yiT, float* __restrict__ y)
{
  __shared__ __align__(16) char sC[32768];  // c  [128 m][128 n]
  __shared__ __align__(16) char sY[32768];  // yi [128 d][128 n]
  int mt = blockIdx.x, dt = blockIdx.y, b = blockIdx.z;
  int m0 = mt * 128, d0 = dt * 128;
  int t = threadIdx.x;
  #pragma unroll
  for (int s = 0; s < 8; ++s) {
    int idx = t + 256 * s;
    int row = idx >> 4, c16 = idx & 15;
    *(int4*)(sC + swz256(row, c16 * 16)) =
        *(const int4*)(cbuf + ((long)b * Mq + m0 + row) * Nq + c16 * 8);
    *(int4*)(sY + swz256(row, c16 * 16)) =
        *(const int4*)(yiT + ((long)b * Dq + d0 + row) * Nq + c16 * 8);
  }
  __syncthreads();
  int w = t >> 6, l = t & 63, la = l & 15, lb = l >> 4;
  f32x4 zero = {0.f, 0.f, 0.f, 0.f};
  f32x4 acc[2][8];
  for (int i = 0; i < 2; ++i) for (int j = 0; j < 8; ++j) acc[i][j] = zero;
  #pragma unroll
  for (int sub = 0; sub < 4; ++sub) {
    int mbyte = sub * 64 + lb * 16;
    bf16x8 af0 = *(const bf16x8*)(sC + swz256(w * 32 + la, mbyte));
    bf16x8 af1 = *(const bf16x8*)(sC + swz256(w * 32 + 16 + la, mbyte));
    bf16x8 bv[8];
    #pragma unroll
    for (int j = 0; j < 8; ++j)
      bv[j] = *(const bf16x8*)(sY + swz256(j * 16 + la, mbyte));
    #pragma unroll
    for (int j = 0; j < 8; ++j) {
      acc[0][j] = __builtin_amdgcn_mfma_f32_16x16x32_bf16(af0, bv[j], acc[0][j], 0, 0, 0);
      acc[1][j] = __builtin_amdgcn_mfma_f32_16x16x32_bf16(af1, bv[j], acc[1][j], 0, 0, 0);
    }
  }
  float* Y = y + ((long)b * Mq + m0) * Dq + d0;
  #pragma unroll
  for (int i = 0; i < 2; ++i)
    #pragma unroll
    for (int j = 0; j < 8; ++j)
      #pragma unroll
      for (int r = 0; r < 4; ++r)
        Y[(long)(w * 32 + i * 16 + lb * 4 + r) * Dq + j * 16 + la] = acc[i][j][r];
}

extern "C" void kernel_launch(void* const* d_in, const int* in_sizes, int n_in,
                              void* d_out, int out_size, void* d_ws, size_t ws_size,
                              hipStream_t stream) {
  const float* x   = (const float*)d_in[0];
  const float* phi = (const float*)d_in[1];
  const float* W1  = (const float*)d_in[2];
  const float* b1  = (const float*)d_in[3];
  const float* W2  = (const float*)d_in[4];
  const float* b2  = (const float*)d_in[5];
  float* y = (float*)d_out;

  char* W = (char*)d_ws;
  __bf16* cbuf  = (__bf16*)W;                      // 16,777,216 B
  __bf16* ebuf  = (__bf16*)(W + 16777216);         // 16,777,216 B
  __bf16* h     = ebuf;                            // aliases ebuf (dead after xi_mfma)
  float*  xipart= (float*)(W + 33554432);          // 16,777,216 B
  float*  g2part= xipart;                          // aliases xipart (dead after xi_reduce)
  __bf16* W1b   = (__bf16*)(W + 50331648);         // 8,388,608 B
  __bf16* W2b   = (__bf16*)(W + 58720256);         // 8,388,608 B
  __bf16* xib   = (__bf16*)(W + 67108864);         // 2,097,152 B
  __bf16* yiT   = (__bf16*)(W + 69206016);         // 2,097,152 B
  float*  psum  = (float*)(W + 71303168);          // 131,072 B
  float*  cinv  = (float*)(W + 71434240);          // 4,096 B

  // 0) weights -> bf16
  wconv<<<4096, 256, 0, stream>>>(W1, (unsigned long long*)W1b, 1048576);
  wconv<<<4096, 256, 0, stream>>>(W2, (unsigned long long*)W2b, 1048576);
  // 1) logits + fused row-softmax epilogue -> ebuf, cbuf
  logits_mfma<<<dim3(Mq / 128, Bq), 256, 0, stream>>>(x, phi, ebuf, cbuf);
  // 2) token-softmax denominators
  colsum_part<<<dim3(32, Bq), 256, 0, stream>>>(ebuf, psum);
  colsum_fin<<<Bq, 128, 0, stream>>>(psum, cinv);
  // 3) xi partials + reduce (cinv applied in reduce)
  xi_mfma<<<dim3(Dq / 64, 4, Bq), 256, 0, stream>>>(ebuf, x, xipart);
  xi_reduce<<<4096, 256, 0, stream>>>(xipart, cinv, xib);
  // 4) h = gelu(xi @ W1 + b1)   [1024 x 4096 x K=1024]
  gemm_bf16<2, __bf16><<<dim3(8, 32, 1), 256, 0, stream>>>(
      xib, W1b, b1, h, Dq, Fq, Fq, 1024, 0L);
  // 5) yi partials = h @ W2     [1024 x 1024 x K=4096, split-K 4]
  gemm_bf16<0, float><<<dim3(8, 8, 4), 256, 0, stream>>>(
      h, W2b, nullptr, g2part, Fq, Dq, Dq, 1024, 1048576L);
  // 6) reduce + b2 -> yiT bf16 [b][d][n]
  g2_reduce<<<4096, 256, 0, stream>>>(g2part, b2, yiT);
  // 7) y = c @ yi (bf16 MFMA)
  combine_mfma<<<dim3(Mq / 128, Dq / 128, Bq), 256, 0, stream>>>(cbuf, yiT, y);
}

// Round 4
// 440.031 us; speedup vs baseline: 5.2244x; 1.0053x over previous
//
#include <hip/hip_runtime.h>
#include <math.h>

#define Bq 8
#define Mq 8192
#define Dq 1024
#define Nq 128
#define Fq 4096

typedef __bf16 bf16x8 __attribute__((ext_vector_type(8)));
typedef float f32x4 __attribute__((ext_vector_type(4)));
union P4 { __bf16 h[4]; unsigned long long u; };
union H8 { int4 v; _Float16 h[8]; };
union B8 { int4 v; __bf16 h[8]; };

// swizzled LDS offsets: XOR byte-bits 4-6 with row&7 (bank spread for ds_read_b128)
__device__ __forceinline__ int swz128(int row, int bcol) {  // rows of 64 bf16 (128 B)
  return row * 128 + (bcol ^ ((row & 7) << 4));
}
__device__ __forceinline__ int swz256(int row, int bcol) {  // rows of 128 bf16 (256 B)
  return row * 256 + (bcol ^ ((row & 7) << 4));
}

// ---------------- weight fp32 -> bf16 ----------------
__global__ __launch_bounds__(256) void wconv(const float* __restrict__ src,
                                             unsigned long long* __restrict__ dst, long n4)
{
  long i = (long)blockIdx.x * 256 + threadIdx.x;
  if (i >= n4) return;
  float4 v = ((const float4*)src)[i];
  P4 p; p.h[0] = (__bf16)v.x; p.h[1] = (__bf16)v.y; p.h[2] = (__bf16)v.z; p.h[3] = (__bf16)v.w;
  dst[i] = p.u;
}

// ---------------- logits = X @ phi via bf16 MFMA ----------------
// epilogue: cbuf[m][n] = row-softmax(l), eT[n][m] = exp(l) (transposed, packed stores)
__global__ __launch_bounds__(256) void logits_mfma(
    const float* __restrict__ x, const float* __restrict__ phi,
    __bf16* __restrict__ eT, __bf16* __restrict__ cbuf)
{
  __shared__ __align__(16) char sA[16384];  // x tile  [128 m][64 k]
  __shared__ __align__(16) char sP[16384];  // phi^T   [128 n][64 k]
  int mt = blockIdx.x, b = blockIdx.y;
  int m0 = mt * 128;
  int t = threadIdx.x;
  int col = t & 127, half = t >> 7;
  int arow = t >> 4, ac4 = t & 15;
  int w = t >> 6, l = t & 63, la = l & 15, lb = l >> 4;

  f32x4 zero = {0.f, 0.f, 0.f, 0.f};
  f32x4 acc[2][8];
  for (int i = 0; i < 2; ++i) for (int j = 0; j < 8; ++j) acc[i][j] = zero;

  for (int k0 = 0; k0 < Dq; k0 += 64) {
    #pragma unroll
    for (int i = 0; i < 8; ++i) {
      int row = arow + 16 * i;
      float4 v = *(const float4*)(x + ((long)b * Mq + m0 + row) * Dq + k0 + ac4 * 4);
      P4 p;
      p.h[0] = (__bf16)v.x; p.h[1] = (__bf16)v.y;
      p.h[2] = (__bf16)v.z; p.h[3] = (__bf16)v.w;
      *(unsigned long long*)(sA + swz128(row, 8 * ac4)) = p.u;
    }
    {
      const float* Pp = phi + (long)(k0 + half * 32) * Nq + col;
      #pragma unroll
      for (int i = 0; i < 32; i += 4) {
        float a0 = Pp[(i + 0) * Nq], a1 = Pp[(i + 1) * Nq];
        float a2 = Pp[(i + 2) * Nq], a3 = Pp[(i + 3) * Nq];
        P4 p;
        p.h[0] = (__bf16)a0; p.h[1] = (__bf16)a1;
        p.h[2] = (__bf16)a2; p.h[3] = (__bf16)a3;
        *(unsigned long long*)(sP + swz128(col, 2 * (half * 32 + i))) = p.u;
      }
    }
    __syncthreads();
    #pragma unroll
    for (int sub = 0; sub < 2; ++sub) {
      int mbyte = sub * 64 + lb * 16;
      bf16x8 af0 = *(const bf16x8*)(sA + swz128(w * 32 + la, mbyte));
      bf16x8 af1 = *(const bf16x8*)(sA + swz128(w * 32 + 16 + la, mbyte));
      bf16x8 bv[8];
      #pragma unroll
      for (int j = 0; j < 8; ++j)
        bv[j] = *(const bf16x8*)(sP + swz128(j * 16 + la, mbyte));
      #pragma unroll
      for (int j = 0; j < 8; ++j) {
        acc[0][j] = __builtin_amdgcn_mfma_f32_16x16x32_bf16(af0, bv[j], acc[0][j], 0, 0, 0);
        acc[1][j] = __builtin_amdgcn_mfma_f32_16x16x32_bf16(af1, bv[j], acc[1][j], 0, 0, 0);
      }
    }
    __syncthreads();
  }
  // per-row (m) softmax denominators over 128 n (max-free, |l| <~ 6)
  float inv[2][4];
  #pragma unroll
  for (int i = 0; i < 2; ++i)
    #pragma unroll
    for (int r = 0; r < 4; ++r) {
      float s = 0.f;
      #pragma unroll
      for (int j = 0; j < 8; ++j) s += __expf(acc[i][j][r]);
      s += __shfl_xor(s, 1); s += __shfl_xor(s, 2);
      s += __shfl_xor(s, 4); s += __shfl_xor(s, 8);
      inv[i][r] = 1.0f / s;
    }
  __bf16* Cb = cbuf + ((long)b * Mq + m0) * Nq;
  __bf16* Eb = eT + (long)b * Nq * Mq + m0;
  #pragma unroll
  for (int i = 0; i < 2; ++i)
    #pragma unroll
    for (int j = 0; j < 8; ++j) {
      P4 p;
      #pragma unroll
      for (int r = 0; r < 4; ++r) {
        int row = w * 32 + i * 16 + lb * 4 + r;
        float e = __expf(acc[i][j][r]);
        p.h[r] = (__bf16)e;
        Cb[(long)row * Nq + j * 16 + la] = (__bf16)(e * inv[i][r]);
      }
      *(unsigned long long*)(Eb + (long)(j * 16 + la) * Mq + w * 32 + i * 16 + lb * 4) = p.u;
    }
}

// ---------------- cinv[b*128+n] = 1 / rowsum(eT) ----------------
__global__ __launch_bounds__(256) void colsum_rows(const __bf16* __restrict__ eT,
                                                   float* __restrict__ cinv)
{
  __shared__ float red[4];
  int r = blockIdx.x;
  int t = threadIdx.x;
  const __bf16* p = eT + (long)r * Mq;
  float s = 0.f;
  #pragma unroll
  for (int k = 0; k < 4; ++k) {
    B8 v; v.v = *(const int4*)(p + t * 8 + k * 2048);
    #pragma unroll
    for (int e = 0; e < 8; ++e) s += (float)v.h[e];
  }
  #pragma unroll
  for (int off = 32; off >= 1; off >>= 1) s += __shfl_down(s, off);
  if ((t & 63) == 0) red[t >> 6] = s;
  __syncthreads();
  if (t == 0) cinv[r] = 1.0f / (red[0] + red[1] + red[2] + red[3]);
}

// ---------------- xi partials: part[kc][b][n][d] = sum_m e[n,m]*x[m,d] ----------------
// block: 128 n x 64 d, m-chunk 1024 (kc of 8); async-stage split (T14)
__global__ __launch_bounds__(256) void xi_mfma(
    const __bf16* __restrict__ eT, const float* __restrict__ x,
    _Float16* __restrict__ part)
{
  __shared__ __align__(16) char sD[16384];  // eT tile [128 n][64 m]
  __shared__ __align__(16) char sX[8192];   // x^T tile [64 d][64 m]
  int dt = blockIdx.x, kc = blockIdx.y, b = blockIdx.z;
  int d0 = dt * 64;
  int t = threadIdx.x;
  int arow = t >> 1, ahalf = t & 1;     // A staging: n row, 32-m half
  const __bf16* Ep0 = eT + ((long)b * Nq + arow) * Mq + (long)kc * 1024 + ahalf * 32;
  int cd = t & 63, grp = t >> 6;        // B staging: d col, 16-m group
  const float* Xp0 = x + ((long)b * Mq + (long)kc * 1024 + grp * 16) * Dq + d0 + cd;
  int w = t >> 6, l = t & 63, la = l & 15, lb = l >> 4;

  f32x4 zero = {0.f, 0.f, 0.f, 0.f};
  f32x4 acc[2][4];
  for (int i = 0; i < 2; ++i) for (int j = 0; j < 4; ++j) acc[i][j] = zero;

  int4 ar[4];
  float br[16];
  // prologue: load + write tile 0
  #pragma unroll
  for (int q = 0; q < 4; ++q) ar[q] = *(const int4*)(Ep0 + q * 8);
  #pragma unroll
  for (int i = 0; i < 16; ++i) br[i] = Xp0[(long)i * Dq];
  #pragma unroll
  for (int q = 0; q < 4; ++q)
    *(int4*)(sD + swz128(arow, ahalf * 64 + q * 16)) = ar[q];
  #pragma unroll
  for (int q = 0; q < 4; ++q) {
    P4 p;
    p.h[0] = (__bf16)br[4 * q + 0]; p.h[1] = (__bf16)br[4 * q + 1];
    p.h[2] = (__bf16)br[4 * q + 2]; p.h[3] = (__bf16)br[4 * q + 3];
    *(unsigned long long*)(sX + swz128(cd, grp * 32 + q * 8)) = p.u;
  }

  for (int it = 0; it < 16; ++it) {
    __syncthreads();
    // issue next tile's global loads into regs (overlap with MFMAs below)
    if (it < 15) {
      #pragma unroll
      for (int q = 0; q < 4; ++q)
        ar[q] = *(const int4*)(Ep0 + (it + 1) * 64 + q * 8);
      #pragma unroll
      for (int i = 0; i < 16; ++i)
        br[i] = Xp0[((long)(it + 1) * 64 + i) * Dq];
    }
    #pragma unroll
    for (int sub = 0; sub < 2; ++sub) {
      int mbyte = sub * 64 + lb * 16;
      bf16x8 af0 = *(const bf16x8*)(sD + swz128(w * 32 + la, mbyte));
      bf16x8 af1 = *(const bf16x8*)(sD + swz128(w * 32 + 16 + la, mbyte));
      bf16x8 bv[4];
      #pragma unroll
      for (int j = 0; j < 4; ++j)
        bv[j] = *(const bf16x8*)(sX + swz128(j * 16 + la, mbyte));
      #pragma unroll
      for (int j = 0; j < 4; ++j) {
        acc[0][j] = __builtin_amdgcn_mfma_f32_16x16x32_bf16(af0, bv[j], acc[0][j], 0, 0, 0);
        acc[1][j] = __builtin_amdgcn_mfma_f32_16x16x32_bf16(af1, bv[j], acc[1][j], 0, 0, 0);
      }
    }
    __syncthreads();
    if (it < 15) {
      #pragma unroll
      for (int q = 0; q < 4; ++q)
        *(int4*)(sD + swz128(arow, ahalf * 64 + q * 16)) = ar[q];
      #pragma unroll
      for (int q = 0; q < 4; ++q) {
        P4 p;
        p.h[0] = (__bf16)br[4 * q + 0]; p.h[1] = (__bf16)br[4 * q + 1];
        p.h[2] = (__bf16)br[4 * q + 2]; p.h[3] = (__bf16)br[4 * q + 3];
        *(unsigned long long*)(sX + swz128(cd, grp * 32 + q * 8)) = p.u;
      }
    }
  }
  _Float16* P = part + ((long)kc * Bq + b) * (long)Nq * Dq + d0;
  #pragma unroll
  for (int i = 0; i < 2; ++i)
    #pragma unroll
    for (int j = 0; j < 4; ++j)
      #pragma unroll
      for (int r = 0; r < 4; ++r)
        P[(long)(w * 32 + i * 16 + lb * 4 + r) * Dq + j * 16 + la] = (_Float16)acc[i][j][r];
}

// ---------------- xi reduce: xib = bf16(cinv[row] * sum_kc part) ----------------
__global__ __launch_bounds__(256) void xi_reduce(const _Float16* __restrict__ part,
    const float* __restrict__ cinv, __bf16* __restrict__ xib)
{
  long base = ((long)blockIdx.x * 256 + threadIdx.x) * 8;   // over 1,048,576 elements
  int row = (int)(base >> 10);
  float civ = cinv[row];
  float s[8] = {};
  #pragma unroll
  for (int k = 0; k < 8; ++k) {
    H8 v; v.v = *(const int4*)(part + (long)k * 1048576 + base);
    #pragma unroll
    for (int e = 0; e < 8; ++e) s[e] += (float)v.h[e];
  }
  B8 o;
  #pragma unroll
  for (int e = 0; e < 8; ++e) o.h[e] = (__bf16)(s[e] * civ);
  *(int4*)(xib + base) = o.v;
}

// ---------------- generic bf16 MFMA GEMM 128x128 tile ----------------
template<int EPI, typename OT>
__global__ __launch_bounds__(256) void gemm_bf16(const __bf16* __restrict__ A,
    const __bf16* __restrict__ Bw, const float* __restrict__ bias,
    OT* __restrict__ C, int lda, int ldb, int ldc, int kLen, long strideCz)
{
  __shared__ __align__(16) char sA[16384];
  __shared__ __align__(16) char sB[16384];
  int m0 = blockIdx.x * 128, n0 = blockIdx.y * 128;
  int kbase = blockIdx.z * kLen;
  C += (long)blockIdx.z * strideCz;
  int t = threadIdx.x;
  int col = t & 127, half = t >> 7;
  int w = t >> 6, l = t & 63, la = l & 15, lb = l >> 4;

  f32x4 zero = {0.f, 0.f, 0.f, 0.f};
  f32x4 acc[2][8];
  for (int i = 0; i < 2; ++i) for (int j = 0; j < 8; ++j) acc[i][j] = zero;

  for (int kt = 0; kt < kLen; kt += 64) {
    int kp = kbase + kt;
    #pragma unroll
    for (int s = 0; s < 4; ++s) {
      int idx = t + 256 * s;
      int row = idx >> 3, c8 = idx & 7;
      *(int4*)(sA + swz128(row, c8 * 16)) =
          *(const int4*)(A + (long)(m0 + row) * lda + kp + c8 * 8);
    }
    {
      const __bf16* Bp = Bw + (long)(kp + half * 32) * ldb + n0 + col;
      #pragma unroll
      for (int i = 0; i < 32; i += 4) {
        P4 p;
        p.h[0] = Bp[(long)(i + 0) * ldb]; p.h[1] = Bp[(long)(i + 1) * ldb];
        p.h[2] = Bp[(long)(i + 2) * ldb]; p.h[3] = Bp[(long)(i + 3) * ldb];
        *(unsigned long long*)(sB + swz128(col, 2 * (half * 32 + i))) = p.u;
      }
    }
    __syncthreads();
    #pragma unroll
    for (int sub = 0; sub < 2; ++sub) {
      int mbyte = sub * 64 + lb * 16;
      bf16x8 af0 = *(const bf16x8*)(sA + swz128(w * 32 + la, mbyte));
      bf16x8 af1 = *(const bf16x8*)(sA + swz128(w * 32 + 16 + la, mbyte));
      bf16x8 bv[8];
      #pragma unroll
      for (int j = 0; j < 8; ++j)
        bv[j] = *(const bf16x8*)(sB + swz128(j * 16 + la, mbyte));
      #pragma unroll
      for (int j = 0; j < 8; ++j) {
        acc[0][j] = __builtin_amdgcn_mfma_f32_16x16x32_bf16(af0, bv[j], acc[0][j], 0, 0, 0);
        acc[1][j] = __builtin_amdgcn_mfma_f32_16x16x32_bf16(af1, bv[j], acc[1][j], 0, 0, 0);
      }
    }
    __syncthreads();
  }
  #pragma unroll
  for (int i = 0; i < 2; ++i)
    #pragma unroll
    for (int j = 0; j < 8; ++j)
      #pragma unroll
      for (int r = 0; r < 4; ++r) {
        int row = m0 + w * 32 + i * 16 + lb * 4 + r;
        int colg = n0 + j * 16 + la;
        float v = acc[i][j][r];
        if (EPI == 2) {
          v += bias[colg];
          v = 0.5f * v * (1.0f + erff(v * 0.70710678118654752f));
        }
        C[(long)row * ldc + colg] = (OT)v;
      }
}

// ---------------- G2 reduce: yiT[b][d][n] = bf16(sum_kc part + b2[d]) ----------------
__global__ __launch_bounds__(256) void g2_reduce(const float* __restrict__ part,
    const float* __restrict__ b2, __bf16* __restrict__ yiT)
{
  long idx = (long)blockIdx.x * 256 + threadIdx.x;   // 1,048,576
  int row = (int)(idx >> 10);       // b*128+n
  int d = (int)(idx & 1023);
  float s = part[idx] + part[idx + 1048576] + part[idx + 2097152] + part[idx + 3145728] + b2[d];
  int b = row >> 7, n = row & 127;
  yiT[((long)b * Dq + d) * Nq + n] = (__bf16)s;
}

// ---------------- combine: y[b,m,d] = sum_n cbuf[m,n] * yiT[d,n] ----------------
__global__ __launch_bounds__(256) void combine_mfma(const __bf16* __restrict__ cbuf,
    const __bf16* __restrict__ yiT, float* __restrict__ y)
{
  __shared__ __align__(16) char sC[32768];  // c  [128 m][128 n]
  __shared__ __align__(16) char sY[32768];  // yi [128 d][128 n]
  int mt = blockIdx.x, dt = blockIdx.y, b = blockIdx.z;
  int m0 = mt * 128, d0 = dt * 128;
  int t = threadIdx.x;
  #pragma unroll
  for (int s = 0; s < 8; ++s) {
    int idx = t + 256 * s;
    int row = idx >> 4, c16 = idx & 15;
    *(int4*)(sC + swz256(row, c16 * 16)) =
        *(const int4*)(cbuf + ((long)b * Mq + m0 + row) * Nq + c16 * 8);
    *(int4*)(sY + swz256(row, c16 * 16)) =
        *(const int4*)(yiT + ((long)b * Dq + d0 + row) * Nq + c16 * 8);
  }
  __syncthreads();
  int w = t >> 6, l = t & 63, la = l & 15, lb = l >> 4;
  f32x4 zero = {0.f, 0.f, 0.f, 0.f};
  f32x4 acc[2][8];
  for (int i = 0; i < 2; ++i) for (int j = 0; j < 8; ++j) acc[i][j] = zero;
  #pragma unroll
  for (int sub = 0; sub < 4; ++sub) {
    int mbyte = sub * 64 + lb * 16;
    bf16x8 af0 = *(const bf16x8*)(sC + swz256(w * 32 + la, mbyte));
    bf16x8 af1 = *(const bf16x8*)(sC + swz256(w * 32 + 16 + la, mbyte));
    bf16x8 bv[8];
    #pragma unroll
    for (int j = 0; j < 8; ++j)
      bv[j] = *(const bf16x8*)(sY + swz256(j * 16 + la, mbyte));
    #pragma unroll
    for (int j = 0; j < 8; ++j) {
      acc[0][j] = __builtin_amdgcn_mfma_f32_16x16x32_bf16(af0, bv[j], acc[0][j], 0, 0, 0);
      acc[1][j] = __builtin_amdgcn_mfma_f32_16x16x32_bf16(af1, bv[j], acc[1][j], 0, 0, 0);
    }
  }
  float* Y = y + ((long)b * Mq + m0) * Dq + d0;
  #pragma unroll
  for (int i = 0; i < 2; ++i)
    #pragma unroll
    for (int j = 0; j < 8; ++j)
      #pragma unroll
      for (int r = 0; r < 4; ++r)
        Y[(long)(w * 32 + i * 16 + lb * 4 + r) * Dq + j * 16 + la] = acc[i][j][r];
}

extern "C" void kernel_launch(void* const* d_in, const int* in_sizes, int n_in,
                              void* d_out, int out_size, void* d_ws, size_t ws_size,
                              hipStream_t stream) {
  const float* x   = (const float*)d_in[0];
  const float* phi = (const float*)d_in[1];
  const float* W1  = (const float*)d_in[2];
  const float* b1  = (const float*)d_in[3];
  const float* W2  = (const float*)d_in[4];
  const float* b2  = (const float*)d_in[5];
  float* y = (float*)d_out;

  char* W = (char*)d_ws;
  __bf16*   cbuf   = (__bf16*)W;                      // 16 MB
  __bf16*   eT     = (__bf16*)(W + 16777216);         // 16 MB  [b][n][m]
  __bf16*   h      = eT;                              // aliases eT (dead after xi_mfma)
  _Float16* part   = (_Float16*)(W + 33554432);       // 16 MB  (8 x 1M fp16)
  float*    g2part = (float*)(W + 33554432);          // aliases part (dead after xi_reduce)
  __bf16*   W1b    = (__bf16*)(W + 50331648);         // 8 MB
  __bf16*   W2b    = (__bf16*)(W + 58720256);         // 8 MB
  __bf16*   xib    = (__bf16*)(W + 67108864);         // 2 MB
  __bf16*   yiT    = (__bf16*)(W + 69206016);         // 2 MB
  float*    cinv   = (float*)(W + 71303168);          // 4 KB

  // 0) weights -> bf16
  wconv<<<4096, 256, 0, stream>>>(W1, (unsigned long long*)W1b, 1048576);
  wconv<<<4096, 256, 0, stream>>>(W2, (unsigned long long*)W2b, 1048576);
  // 1) logits + fused epilogue -> eT (exp, transposed), cbuf (row-softmax)
  logits_mfma<<<dim3(Mq / 128, Bq), 256, 0, stream>>>(x, phi, eT, cbuf);
  // 2) token-softmax denominators: coalesced row sums of eT
  colsum_rows<<<Bq * Nq, 256, 0, stream>>>(eT, cinv);
  // 3) xi partials (split-K 8, fp16 partials) + reduce
  xi_mfma<<<dim3(Dq / 64, 8, Bq), 256, 0, stream>>>(eT, x, part);
  xi_reduce<<<512, 256, 0, stream>>>(part, cinv, xib);
  // 4) h = gelu(xi @ W1 + b1)
  gemm_bf16<2, __bf16><<<dim3(8, 32, 1), 256, 0, stream>>>(
      xib, W1b, b1, h, Dq, Fq, Fq, 1024, 0L);
  // 5) yi partials = h @ W2 (split-K 4)
  gemm_bf16<0, float><<<dim3(8, 8, 4), 256, 0, stream>>>(
      h, W2b, nullptr, g2part, Fq, Dq, Dq, 1024, 1048576L);
  // 6) reduce + b2 -> yiT bf16 [b][d][n]
  g2_reduce<<<4096, 256, 0, stream>>>(g2part, b2, yiT);
  // 7) y = c @ yi (bf16 MFMA)
  combine_mfma<<<dim3(Mq / 128, Dq / 128, Bq), 256, 0, stream>>>(cbuf, yiT, y);
}

// Round 5
// 377.333 us; speedup vs baseline: 6.0925x; 1.1662x over previous
//
#include <hip/hip_runtime.h>
#include <math.h>

#define Bq 8
#define Mq 8192
#define Dq 1024
#define Nq 128
#define Fq 4096

typedef __bf16 bf16x8 __attribute__((ext_vector_type(8)));
typedef float f32x4 __attribute__((ext_vector_type(4)));
union P4 { __bf16 h[4]; unsigned long long u; };
union H8 { int4 v; _Float16 h[8]; };
union B8 { int4 v; __bf16 h[8]; };

// swizzled LDS offsets: XOR byte-bits 4-6 with row&7 (bank spread for ds_read_b128)
__device__ __forceinline__ int swz128(int row, int bcol) {  // rows of 64 bf16 (128 B)
  return row * 128 + (bcol ^ ((row & 7) << 4));
}
__device__ __forceinline__ int swz256(int row, int bcol) {  // rows of 128 bf16 (256 B)
  return row * 256 + (bcol ^ ((row & 7) << 4));
}

// ---------------- weight fp32 -> bf16 ----------------
__global__ __launch_bounds__(256) void wconv(const float* __restrict__ src,
                                             unsigned long long* __restrict__ dst, long n4)
{
  long i = (long)blockIdx.x * 256 + threadIdx.x;
  if (i >= n4) return;
  float4 v = ((const float4*)src)[i];
  P4 p; p.h[0] = (__bf16)v.x; p.h[1] = (__bf16)v.y; p.h[2] = (__bf16)v.z; p.h[3] = (__bf16)v.w;
  dst[i] = p.u;
}

// ---------------- logits = X @ phi via bf16 MFMA ----------------
// epilogue: cbuf[m][n] = row-softmax(l), eT[n][m] = exp(l) (transposed, packed stores)
__global__ __launch_bounds__(256) void logits_mfma(
    const float* __restrict__ x, const float* __restrict__ phi,
    __bf16* __restrict__ eT, __bf16* __restrict__ cbuf)
{
  __shared__ __align__(16) char sA[16384];  // x tile  [128 m][64 k]
  __shared__ __align__(16) char sP[16384];  // phi^T   [128 n][64 k]
  int mt = blockIdx.x, b = blockIdx.y;
  int m0 = mt * 128;
  int t = threadIdx.x;
  int col = t & 127, half = t >> 7;
  int arow = t >> 4, ac4 = t & 15;
  int w = t >> 6, l = t & 63, la = l & 15, lb = l >> 4;

  f32x4 zero = {0.f, 0.f, 0.f, 0.f};
  f32x4 acc[2][8];
  for (int i = 0; i < 2; ++i) for (int j = 0; j < 8; ++j) acc[i][j] = zero;

  for (int k0 = 0; k0 < Dq; k0 += 64) {
    #pragma unroll
    for (int i = 0; i < 8; ++i) {
      int row = arow + 16 * i;
      float4 v = *(const float4*)(x + ((long)b * Mq + m0 + row) * Dq + k0 + ac4 * 4);
      P4 p;
      p.h[0] = (__bf16)v.x; p.h[1] = (__bf16)v.y;
      p.h[2] = (__bf16)v.z; p.h[3] = (__bf16)v.w;
      *(unsigned long long*)(sA + swz128(row, 8 * ac4)) = p.u;
    }
    {
      const float* Pp = phi + (long)(k0 + half * 32) * Nq + col;
      #pragma unroll
      for (int i = 0; i < 32; i += 4) {
        float a0 = Pp[(i + 0) * Nq], a1 = Pp[(i + 1) * Nq];
        float a2 = Pp[(i + 2) * Nq], a3 = Pp[(i + 3) * Nq];
        P4 p;
        p.h[0] = (__bf16)a0; p.h[1] = (__bf16)a1;
        p.h[2] = (__bf16)a2; p.h[3] = (__bf16)a3;
        *(unsigned long long*)(sP + swz128(col, 2 * (half * 32 + i))) = p.u;
      }
    }
    __syncthreads();
    #pragma unroll
    for (int sub = 0; sub < 2; ++sub) {
      int mbyte = sub * 64 + lb * 16;
      bf16x8 af0 = *(const bf16x8*)(sA + swz128(w * 32 + la, mbyte));
      bf16x8 af1 = *(const bf16x8*)(sA + swz128(w * 32 + 16 + la, mbyte));
      bf16x8 bv[8];
      #pragma unroll
      for (int j = 0; j < 8; ++j)
        bv[j] = *(const bf16x8*)(sP + swz128(j * 16 + la, mbyte));
      #pragma unroll
      for (int j = 0; j < 8; ++j) {
        acc[0][j] = __builtin_amdgcn_mfma_f32_16x16x32_bf16(af0, bv[j], acc[0][j], 0, 0, 0);
        acc[1][j] = __builtin_amdgcn_mfma_f32_16x16x32_bf16(af1, bv[j], acc[1][j], 0, 0, 0);
      }
    }
    __syncthreads();
  }
  // per-row (m) softmax denominators over 128 n (max-free, |l| <~ 6)
  float inv[2][4];
  #pragma unroll
  for (int i = 0; i < 2; ++i)
    #pragma unroll
    for (int r = 0; r < 4; ++r) {
      float s = 0.f;
      #pragma unroll
      for (int j = 0; j < 8; ++j) s += __expf(acc[i][j][r]);
      s += __shfl_xor(s, 1); s += __shfl_xor(s, 2);
      s += __shfl_xor(s, 4); s += __shfl_xor(s, 8);
      inv[i][r] = 1.0f / s;
    }
  __bf16* Cb = cbuf + ((long)b * Mq + m0) * Nq;
  __bf16* Eb = eT + (long)b * Nq * Mq + m0;
  #pragma unroll
  for (int i = 0; i < 2; ++i)
    #pragma unroll
    for (int j = 0; j < 8; ++j) {
      P4 p;
      #pragma unroll
      for (int r = 0; r < 4; ++r) {
        int row = w * 32 + i * 16 + lb * 4 + r;
        float e = __expf(acc[i][j][r]);
        p.h[r] = (__bf16)e;
        Cb[(long)row * Nq + j * 16 + la] = (__bf16)(e * inv[i][r]);
      }
      *(unsigned long long*)(Eb + (long)(j * 16 + la) * Mq + w * 32 + i * 16 + lb * 4) = p.u;
    }
}

// ---------------- cinv[b*128+n] = 1 / rowsum(eT) ----------------
__global__ __launch_bounds__(256) void colsum_rows(const __bf16* __restrict__ eT,
                                                   float* __restrict__ cinv)
{
  __shared__ float red[4];
  int r = blockIdx.x;
  int t = threadIdx.x;
  const __bf16* p = eT + (long)r * Mq;
  float s = 0.f;
  #pragma unroll
  for (int k = 0; k < 4; ++k) {
    B8 v; v.v = *(const int4*)(p + t * 8 + k * 2048);
    #pragma unroll
    for (int e = 0; e < 8; ++e) s += (float)v.h[e];
  }
  #pragma unroll
  for (int off = 32; off >= 1; off >>= 1) s += __shfl_down(s, off);
  if ((t & 63) == 0) red[t >> 6] = s;
  __syncthreads();
  if (t == 0) cinv[r] = 1.0f / (red[0] + red[1] + red[2] + red[3]);
}

// ---------------- xi partials: part[kc][b][n][d] = sum_m e[n,m]*x[m,d] ----------------
// block: 128 n x 128 d, m-chunk 1024 (kc of 8); grid 512 (XCD-chunked swizzle)
// x read in 512B granules (2 m-rows x 128 d per wave-instr); T14 reg prefetch
__global__ __launch_bounds__(256) void xi_mfma(
    const __bf16* __restrict__ eT, const float* __restrict__ x,
    _Float16* __restrict__ part)
{
  __shared__ __align__(16) char sD[16384];  // eT tile [128 n][64 m]
  __shared__ __align__(16) char sX[16384];  // x^T tile [128 d][64 m]
  int lin = blockIdx.x;
  int wk = (lin & 7) * 64 + (lin >> 3);     // same-eT-chunk blocks -> same XCD
  int dts = wk & 7, kc = (wk >> 3) & 7, b = wk >> 6;
  int d0 = dts * 128;
  int t = threadIdx.x;
  int w = t >> 6, l = t & 63, la = l & 15, lb = l >> 4;
  // A staging: 4 int4 per thread
  int arow = t >> 1, ahalf = t & 1;
  const __bf16* Ep0 = eT + ((long)b * Nq + arow) * Mq + kc * 1024 + ahalf * 32;
  // B staging: per wave-instr 2 m-rows x 128 d (two 512B runs)
  int bm = w * 2 + (l >> 5), bd = (l & 31) * 4;
  const float* Xp0 = x + ((long)b * Mq + kc * 1024 + bm) * Dq + d0 + bd;

  f32x4 zero = {0.f, 0.f, 0.f, 0.f};
  f32x4 acc[2][8];
  for (int i = 0; i < 2; ++i) for (int j = 0; j < 8; ++j) acc[i][j] = zero;

  int4 ar[4];
  float br[8][4];
  // prologue: tile 0
  #pragma unroll
  for (int q = 0; q < 4; ++q) ar[q] = *(const int4*)(Ep0 + q * 8);
  #pragma unroll
  for (int k = 0; k < 8; ++k) *(float4*)br[k] = *(const float4*)(Xp0 + (long)k * 8 * Dq);
  #pragma unroll
  for (int q = 0; q < 4; ++q) *(int4*)(sD + swz128(arow, ahalf * 64 + q * 16)) = ar[q];
  #pragma unroll
  for (int k = 0; k < 8; ++k)
    #pragma unroll
    for (int q = 0; q < 4; ++q)
      *(__bf16*)(sX + swz128(bd + q, 2 * (k * 8 + bm))) = (__bf16)br[k][q];

  for (int it = 0; it < 16; ++it) {
    __syncthreads();
    if (it < 15) {  // issue next tile's loads; they complete under the MFMAs
      #pragma unroll
      for (int q = 0; q < 4; ++q) ar[q] = *(const int4*)(Ep0 + (it + 1) * 64 + q * 8);
      #pragma unroll
      for (int k = 0; k < 8; ++k)
        *(float4*)br[k] = *(const float4*)(Xp0 + ((long)(it + 1) * 64 + k * 8) * Dq);
    }
    #pragma unroll
    for (int sub = 0; sub < 2; ++sub) {
      int mbyte = sub * 64 + lb * 16;
      bf16x8 af0 = *(const bf16x8*)(sD + swz128(w * 32 + la, mbyte));
      bf16x8 af1 = *(const bf16x8*)(sD + swz128(w * 32 + 16 + la, mbyte));
      #pragma unroll
      for (int j = 0; j < 8; ++j) {
        bf16x8 bv = *(const bf16x8*)(sX + swz128(j * 16 + la, mbyte));
        acc[0][j] = __builtin_amdgcn_mfma_f32_16x16x32_bf16(af0, bv, acc[0][j], 0, 0, 0);
        acc[1][j] = __builtin_amdgcn_mfma_f32_16x16x32_bf16(af1, bv, acc[1][j], 0, 0, 0);
      }
    }
    __syncthreads();
    if (it < 15) {
      #pragma unroll
      for (int q = 0; q < 4; ++q) *(int4*)(sD + swz128(arow, ahalf * 64 + q * 16)) = ar[q];
      #pragma unroll
      for (int k = 0; k < 8; ++k)
        #pragma unroll
        for (int q = 0; q < 4; ++q)
          *(__bf16*)(sX + swz128(bd + q, 2 * (k * 8 + bm))) = (__bf16)br[k][q];
    }
  }
  _Float16* P = part + ((long)kc * Bq + b) * (long)Nq * Dq + d0;
  #pragma unroll
  for (int i = 0; i < 2; ++i)
    #pragma unroll
    for (int j = 0; j < 8; ++j)
      #pragma unroll
      for (int r = 0; r < 4; ++r)
        P[(long)(w * 32 + i * 16 + lb * 4 + r) * Dq + j * 16 + la] = (_Float16)acc[i][j][r];
}

// ---------------- xi reduce: xib = bf16(cinv[row] * sum_kc part) ----------------
__global__ __launch_bounds__(256) void xi_reduce(const _Float16* __restrict__ part,
    const float* __restrict__ cinv, __bf16* __restrict__ xib)
{
  long base = ((long)blockIdx.x * 256 + threadIdx.x) * 8;   // over 1,048,576 elements
  int row = (int)(base >> 10);
  float civ = cinv[row];
  float s[8] = {};
  #pragma unroll
  for (int k = 0; k < 8; ++k) {
    H8 v; v.v = *(const int4*)(part + (long)k * 1048576 + base);
    #pragma unroll
    for (int e = 0; e < 8; ++e) s[e] += (float)v.h[e];
  }
  B8 o;
  #pragma unroll
  for (int e = 0; e < 8; ++e) o.h[e] = (__bf16)(s[e] * civ);
  *(int4*)(xib + base) = o.v;
}

// ---------------- generic bf16 MFMA GEMM 128x128 tile ----------------
template<int EPI, typename OT>
__global__ __launch_bounds__(256) void gemm_bf16(const __bf16* __restrict__ A,
    const __bf16* __restrict__ Bw, const float* __restrict__ bias,
    OT* __restrict__ C, int lda, int ldb, int ldc, int kLen, long strideCz)
{
  __shared__ __align__(16) char sA[16384];
  __shared__ __align__(16) char sB[16384];
  int m0 = blockIdx.x * 128, n0 = blockIdx.y * 128;
  int kbase = blockIdx.z * kLen;
  C += (long)blockIdx.z * strideCz;
  int t = threadIdx.x;
  int col = t & 127, half = t >> 7;
  int w = t >> 6, l = t & 63, la = l & 15, lb = l >> 4;

  f32x4 zero = {0.f, 0.f, 0.f, 0.f};
  f32x4 acc[2][8];
  for (int i = 0; i < 2; ++i) for (int j = 0; j < 8; ++j) acc[i][j] = zero;

  for (int kt = 0; kt < kLen; kt += 64) {
    int kp = kbase + kt;
    #pragma unroll
    for (int s = 0; s < 4; ++s) {
      int idx = t + 256 * s;
      int row = idx >> 3, c8 = idx & 7;
      *(int4*)(sA + swz128(row, c8 * 16)) =
          *(const int4*)(A + (long)(m0 + row) * lda + kp + c8 * 8);
    }
    {
      const __bf16* Bp = Bw + (long)(kp + half * 32) * ldb + n0 + col;
      #pragma unroll
      for (int i = 0; i < 32; i += 4) {
        P4 p;
        p.h[0] = Bp[(long)(i + 0) * ldb]; p.h[1] = Bp[(long)(i + 1) * ldb];
        p.h[2] = Bp[(long)(i + 2) * ldb]; p.h[3] = Bp[(long)(i + 3) * ldb];
        *(unsigned long long*)(sB + swz128(col, 2 * (half * 32 + i))) = p.u;
      }
    }
    __syncthreads();
    #pragma unroll
    for (int sub = 0; sub < 2; ++sub) {
      int mbyte = sub * 64 + lb * 16;
      bf16x8 af0 = *(const bf16x8*)(sA + swz128(w * 32 + la, mbyte));
      bf16x8 af1 = *(const bf16x8*)(sA + swz128(w * 32 + 16 + la, mbyte));
      bf16x8 bv[8];
      #pragma unroll
      for (int j = 0; j < 8; ++j)
        bv[j] = *(const bf16x8*)(sB + swz128(j * 16 + la, mbyte));
      #pragma unroll
      for (int j = 0; j < 8; ++j) {
        acc[0][j] = __builtin_amdgcn_mfma_f32_16x16x32_bf16(af0, bv[j], acc[0][j], 0, 0, 0);
        acc[1][j] = __builtin_amdgcn_mfma_f32_16x16x32_bf16(af1, bv[j], acc[1][j], 0, 0, 0);
      }
    }
    __syncthreads();
  }
  #pragma unroll
  for (int i = 0; i < 2; ++i)
    #pragma unroll
    for (int j = 0; j < 8; ++j)
      #pragma unroll
      for (int r = 0; r < 4; ++r) {
        int row = m0 + w * 32 + i * 16 + lb * 4 + r;
        int colg = n0 + j * 16 + la;
        float v = acc[i][j][r];
        if (EPI == 2) {
          v += bias[colg];
          v = 0.5f * v * (1.0f + erff(v * 0.70710678118654752f));
        }
        C[(long)row * ldc + colg] = (OT)v;
      }
}

// ---------------- G2 reduce: yiT[b][d][n] = bf16(sum_kc part + b2[d]) ----------------
__global__ __launch_bounds__(256) void g2_reduce(const float* __restrict__ part,
    const float* __restrict__ b2, __bf16* __restrict__ yiT)
{
  long idx = (long)blockIdx.x * 256 + threadIdx.x;   // 1,048,576
  int row = (int)(idx >> 10);       // b*128+n
  int d = (int)(idx & 1023);
  float s = part[idx] + part[idx + 1048576] + part[idx + 2097152] + part[idx + 3145728] + b2[d];
  int b = row >> 7, n = row & 127;
  yiT[((long)b * Dq + d) * Nq + n] = (__bf16)s;
}

// ---------------- combine: y[b,m,d] = sum_n cbuf[m,n] * yiT[d,n] ----------------
// 1D grid 4096, dt-fastest work order + XCD-chunked swizzle (cbuf m-tile sharing)
__global__ __launch_bounds__(256) void combine_mfma(const __bf16* __restrict__ cbuf,
    const __bf16* __restrict__ yiT, float* __restrict__ y)
{
  __shared__ __align__(16) char sC[32768];  // c  [128 m][128 n]
  __shared__ __align__(16) char sY[32768];  // yi [128 d][128 n]
  int lin = blockIdx.x;
  int wk = (lin & 7) * 512 + (lin >> 3);
  int dt = wk & 7, mt = (wk >> 3) & 63, b = wk >> 9;
  int m0 = mt * 128, d0 = dt * 128;
  int t = threadIdx.x;
  #pragma unroll
  for (int s = 0; s < 8; ++s) {
    int idx = t + 256 * s;
    int row = idx >> 4, c16 = idx & 15;
    *(int4*)(sC + swz256(row, c16 * 16)) =
        *(const int4*)(cbuf + ((long)b * Mq + m0 + row) * Nq + c16 * 8);
    *(int4*)(sY + swz256(row, c16 * 16)) =
        *(const int4*)(yiT + ((long)b * Dq + d0 + row) * Nq + c16 * 8);
  }
  __syncthreads();
  int w = t >> 6, l = t & 63, la = l & 15, lb = l >> 4;
  f32x4 zero = {0.f, 0.f, 0.f, 0.f};
  f32x4 acc[2][8];
  for (int i = 0; i < 2; ++i) for (int j = 0; j < 8; ++j) acc[i][j] = zero;
  #pragma unroll
  for (int sub = 0; sub < 4; ++sub) {
    int mbyte = sub * 64 + lb * 16;
    bf16x8 af0 = *(const bf16x8*)(sC + swz256(w * 32 + la, mbyte));
    bf16x8 af1 = *(const bf16x8*)(sC + swz256(w * 32 + 16 + la, mbyte));
    bf16x8 bv[8];
    #pragma unroll
    for (int j = 0; j < 8; ++j)
      bv[j] = *(const bf16x8*)(sY + swz256(j * 16 + la, mbyte));
    #pragma unroll
    for (int j = 0; j < 8; ++j) {
      acc[0][j] = __builtin_amdgcn_mfma_f32_16x16x32_bf16(af0, bv[j], acc[0][j], 0, 0, 0);
      acc[1][j] = __builtin_amdgcn_mfma_f32_16x16x32_bf16(af1, bv[j], acc[1][j], 0, 0, 0);
    }
  }
  float* Y = y + ((long)b * Mq + m0) * Dq + d0;
  #pragma unroll
  for (int i = 0; i < 2; ++i)
    #pragma unroll
    for (int j = 0; j < 8; ++j)
      #pragma unroll
      for (int r = 0; r < 4; ++r)
        Y[(long)(w * 32 + i * 16 + lb * 4 + r) * Dq + j * 16 + la] = acc[i][j][r];
}

extern "C" void kernel_launch(void* const* d_in, const int* in_sizes, int n_in,
                              void* d_out, int out_size, void* d_ws, size_t ws_size,
                              hipStream_t stream) {
  const float* x   = (const float*)d_in[0];
  const float* phi = (const float*)d_in[1];
  const float* W1  = (const float*)d_in[2];
  const float* b1  = (const float*)d_in[3];
  const float* W2  = (const float*)d_in[4];
  const float* b2  = (const float*)d_in[5];
  float* y = (float*)d_out;

  char* W = (char*)d_ws;
  __bf16*   cbuf   = (__bf16*)W;                      // 16 MB
  __bf16*   eT     = (__bf16*)(W + 16777216);         // 16 MB  [b][n][m]
  __bf16*   h      = eT;                              // aliases eT (dead after xi_mfma)
  _Float16* part   = (_Float16*)(W + 33554432);       // 16 MB  (8 x 1M fp16)
  float*    g2part = (float*)(W + 33554432);          // aliases part (dead after xi_reduce)
  __bf16*   W1b    = (__bf16*)(W + 50331648);         // 8 MB
  __bf16*   W2b    = (__bf16*)(W + 58720256);         // 8 MB
  __bf16*   xib    = (__bf16*)(W + 67108864);         // 2 MB
  __bf16*   yiT    = (__bf16*)(W + 69206016);         // 2 MB
  float*    cinv   = (float*)(W + 71303168);          // 4 KB

  // 0) weights -> bf16
  wconv<<<4096, 256, 0, stream>>>(W1, (unsigned long long*)W1b, 1048576);
  wconv<<<4096, 256, 0, stream>>>(W2, (unsigned long long*)W2b, 1048576);
  // 1) logits + fused epilogue -> eT (exp, transposed), cbuf (row-softmax)
  logits_mfma<<<dim3(Mq / 128, Bq), 256, 0, stream>>>(x, phi, eT, cbuf);
  // 2) token-softmax denominators: coalesced row sums of eT
  colsum_rows<<<Bq * Nq, 256, 0, stream>>>(eT, cinv);
  // 3) xi partials (128-wide d tiles, split-K 8, fp16 partials) + reduce
  xi_mfma<<<512, 256, 0, stream>>>(eT, x, part);
  xi_reduce<<<512, 256, 0, stream>>>(part, cinv, xib);
  // 4) h = gelu(xi @ W1 + b1)
  gemm_bf16<2, __bf16><<<dim3(8, 32, 1), 256, 0, stream>>>(
      xib, W1b, b1, h, Dq, Fq, Fq, 1024, 0L);
  // 5) yi partials = h @ W2 (split-K 4)
  gemm_bf16<0, float><<<dim3(8, 8, 4), 256, 0, stream>>>(
      h, W2b, nullptr, g2part, Fq, Dq, Dq, 1024, 1048576L);
  // 6) reduce + b2 -> yiT bf16 [b][d][n]
  g2_reduce<<<4096, 256, 0, stream>>>(g2part, b2, yiT);
  // 7) y = c @ yi (bf16 MFMA)
  combine_mfma<<<4096, 256, 0, stream>>>(cbuf, yiT, y);
}